// Round 3
// baseline (45.058 us; speedup 1.0000x reference)
//
#include <hip/hip_runtime.h>

// LengthRegulator (fused single kernel):
//   out[b,t,:] = x[b, searchsorted(cumsum(dur[b]), t, 'right').clip(0,S-1), :] * (t < mel_len[b])
// Shapes: x (32,256,384) f32, duration (32,256) int32, max_len = 4096.
// Output layout: flat [32*4096*384] f32 ++ [32] mel_len-as-f32.
//
// Each block re-computes its batch's cumsum locally (wave-shuffle scan over
// 256 durations), then streams ROWS=32 output rows (48 KB) with nontemporal
// 16B stores (native clang vector type — HIP float4 is rejected by the builtin).

typedef float f32x4 __attribute__((ext_vector_type(4)));

constexpr int B    = 32;
constexpr int S    = 256;
constexpr int D    = 384;
constexpr int ML   = 4096;
constexpr int D4   = D / 4;      // 96 16B-chunks per row
constexpr int ROWS = 32;         // output rows per block
constexpr int TB   = 256;        // threads per block
constexpr int RPB  = ML / ROWS;  // 128 row-blocks per batch

__global__ __launch_bounds__(TB) void lr_fused_kernel(const f32x4* __restrict__ x,
                                                      const int*   __restrict__ dur,
                                                      f32x4*       __restrict__ out,
                                                      float*       __restrict__ mel_out) {
    const int b      = blockIdx.x / RPB;
    const int rowblk = blockIdx.x % RPB;
    const int tid    = threadIdx.x;

    __shared__ int scum[S];
    __shared__ int wsum[TB / 64];
    __shared__ int sidx[ROWS];

    // ---- inclusive scan of dur[b, :] into scum ----
    int v = dur[b * S + tid];
    // wave-local inclusive scan (64 lanes, 6 rounds, no barriers)
    #pragma unroll
    for (int off = 1; off < 64; off <<= 1) {
        int n = __shfl_up(v, off, 64);
        if ((tid & 63) >= off) v += n;
    }
    if ((tid & 63) == 63) wsum[tid >> 6] = v;
    __syncthreads();
    int add = 0;
    const int w = tid >> 6;
    #pragma unroll
    for (int i = 0; i < TB / 64; ++i)
        if (i < w) add += wsum[i];
    v += add;
    scum[tid] = v;
    __syncthreads();

    const int mel = scum[S - 1];
    if (rowblk == 0 && tid == S - 1) mel_out[b] = (float)v;  // v == scum[S-1] here

    // ---- one binary search per output row (searchsorted right, clipped) ----
    if (tid < ROWS) {
        const int t = rowblk * ROWS + tid;
        int lo = 0, hi = S;
        while (lo < hi) {
            const int mid = (lo + hi) >> 1;
            if (scum[mid] <= t) lo = mid + 1; else hi = mid;
        }
        sidx[tid] = (lo < S) ? lo : (S - 1);
    }
    __syncthreads();

    // ---- gather rows from x (L2-resident), stream stores nontemporally ----
    const f32x4* xb = x + (size_t)b * S * D4;
    f32x4* ob = out + ((size_t)b * ML + (size_t)rowblk * ROWS) * D4;
    const f32x4 z = (f32x4){0.f, 0.f, 0.f, 0.f};

    #pragma unroll
    for (int j = tid; j < ROWS * D4; j += TB) {
        const int tl = j / D4;
        const int d4 = j - tl * D4;
        const int t  = rowblk * ROWS + tl;
        f32x4 vv = (t < mel) ? xb[(size_t)sidx[tl] * D4 + d4] : z;
        __builtin_nontemporal_store(vv, &ob[j]);
    }
}

extern "C" void kernel_launch(void* const* d_in, const int* in_sizes, int n_in,
                              void* d_out, int out_size, void* d_ws, size_t ws_size,
                              hipStream_t stream) {
    const float* x   = (const float*)d_in[0];
    const int*   dur = (const int*)d_in[1];
    float* out = (float*)d_out;
    float* mel_out = out + (size_t)B * ML * D;  // output-1 tail

    lr_fused_kernel<<<B * RPB, TB, 0, stream>>>(
        (const f32x4*)x, dur, (f32x4*)out, mel_out);
}

// Round 4
// 35.481 us; speedup vs baseline: 1.2699x; 1.2699x over previous
//
#include <hip/hip_runtime.h>

// LengthRegulator (fused single kernel):
//   out[b,t,:] = x[b, searchsorted(cumsum(dur[b]), t, 'right').clip(0,S-1), :] * (t < mel_len[b])
// Shapes: x (32,256,384) f32, duration (32,256) int32, max_len = 4096.
// Output layout: flat [32*4096*384] f32 ++ [32] mel_len-as-f32.
//
// Each block re-computes its batch's cumsum locally (wave-shuffle scan over
// 256 durations), then streams ROWS=32 output rows (48 KB) of float4 stores.
// NOTE: nontemporal stores REGRESSED (45.1 vs 39.5 µs) — regular stores keep
// the L2 write path that fillBufferAligned demonstrates at 6.9 TB/s.

typedef float f32x4 __attribute__((ext_vector_type(4)));

constexpr int B    = 32;
constexpr int S    = 256;
constexpr int D    = 384;
constexpr int ML   = 4096;
constexpr int D4   = D / 4;      // 96 16B-chunks per row
constexpr int ROWS = 32;         // output rows per block
constexpr int TB   = 256;        // threads per block
constexpr int RPB  = ML / ROWS;  // 128 row-blocks per batch

__global__ __launch_bounds__(TB) void lr_fused_kernel(const f32x4* __restrict__ x,
                                                      const int*   __restrict__ dur,
                                                      f32x4*       __restrict__ out,
                                                      float*       __restrict__ mel_out) {
    const int b      = blockIdx.x / RPB;
    const int rowblk = blockIdx.x % RPB;
    const int tid    = threadIdx.x;

    __shared__ int scum[S];
    __shared__ int wsum[TB / 64];
    __shared__ int sidx[ROWS];

    // ---- inclusive scan of dur[b, :] into scum ----
    int v = dur[b * S + tid];
    // wave-local inclusive scan (64 lanes, 6 rounds, no barriers)
    #pragma unroll
    for (int off = 1; off < 64; off <<= 1) {
        int n = __shfl_up(v, off, 64);
        if ((tid & 63) >= off) v += n;
    }
    if ((tid & 63) == 63) wsum[tid >> 6] = v;
    __syncthreads();
    int add = 0;
    const int w = tid >> 6;
    #pragma unroll
    for (int i = 0; i < TB / 64; ++i)
        if (i < w) add += wsum[i];
    v += add;
    scum[tid] = v;
    __syncthreads();

    const int mel = scum[S - 1];
    if (rowblk == 0 && tid == S - 1) mel_out[b] = (float)v;  // v == scum[S-1] here

    // ---- one binary search per output row (searchsorted right, clipped) ----
    if (tid < ROWS) {
        const int t = rowblk * ROWS + tid;
        int lo = 0, hi = S;
        while (lo < hi) {
            const int mid = (lo + hi) >> 1;
            if (scum[mid] <= t) lo = mid + 1; else hi = mid;
        }
        sidx[tid] = (lo < S) ? lo : (S - 1);
    }
    __syncthreads();

    // ---- gather rows from x (L2-resident), coalesced float4 stores ----
    const f32x4* xb = x + (size_t)b * S * D4;
    f32x4* ob = out + ((size_t)b * ML + (size_t)rowblk * ROWS) * D4;
    const f32x4 z = (f32x4){0.f, 0.f, 0.f, 0.f};

    #pragma unroll
    for (int j = tid; j < ROWS * D4; j += TB) {
        const int tl = j / D4;
        const int d4 = j - tl * D4;
        const int t  = rowblk * ROWS + tl;
        f32x4 vv = (t < mel) ? xb[(size_t)sidx[tl] * D4 + d4] : z;
        ob[j] = vv;
    }
}

extern "C" void kernel_launch(void* const* d_in, const int* in_sizes, int n_in,
                              void* d_out, int out_size, void* d_ws, size_t ws_size,
                              hipStream_t stream) {
    const float* x   = (const float*)d_in[0];
    const int*   dur = (const int*)d_in[1];
    float* out = (float*)d_out;
    float* mel_out = out + (size_t)B * ML * D;  // output-1 tail

    lr_fused_kernel<<<B * RPB, TB, 0, stream>>>(
        (const f32x4*)x, dur, (f32x4*)out, mel_out);
}

// Round 5
// 34.775 us; speedup vs baseline: 1.2957x; 1.0203x over previous
//
#include <hip/hip_runtime.h>

// LengthRegulator (fused single kernel):
//   out[b,t,:] = x[b, searchsorted(cumsum(dur[b]), t, 'right').clip(0,S-1), :] * (t < mel_len[b])
// Shapes: x (32,256,384) f32, duration (32,256) int32, max_len = 4096.
// Output layout: flat [32*4096*384] f32 ++ [32] mel_len-as-f32.
//
// Each block re-computes its batch's cumsum locally (wave-shuffle scan),
// then streams ROWS=32 output rows (48 KB) of coalesced float4 stores.
// NOTE: nontemporal stores REGRESSED (45.1 vs 39.5 µs) — keep regular stores.
// This round: XCD-aware block swizzle so each XCD's 512 blocks cover exactly
// 4 batches -> gather working set 1.5 MB/XCD, L2-resident.

typedef float f32x4 __attribute__((ext_vector_type(4)));

constexpr int B    = 32;
constexpr int S    = 256;
constexpr int D    = 384;
constexpr int ML   = 4096;
constexpr int D4   = D / 4;      // 96 16B-chunks per row
constexpr int ROWS = 32;         // output rows per block
constexpr int TB   = 256;        // threads per block
constexpr int RPB  = ML / ROWS;  // 128 row-blocks per batch
constexpr int NWG  = B * RPB;    // 4096 workgroups
constexpr int NXCD = 8;
constexpr int CPX  = NWG / NXCD; // 512 blocks per XCD chunk (exact)

__global__ __launch_bounds__(TB) void lr_fused_kernel(const f32x4* __restrict__ x,
                                                      const int*   __restrict__ dur,
                                                      f32x4*       __restrict__ out,
                                                      float*       __restrict__ mel_out) {
    // XCD-aware swizzle: hardware round-robins blockIdx%8 across XCDs; remap
    // so each XCD gets a contiguous range of (batch, rowblk) work.
    const int bid    = (blockIdx.x & (NXCD - 1)) * CPX + (blockIdx.x >> 3);
    const int b      = bid / RPB;
    const int rowblk = bid % RPB;
    const int tid    = threadIdx.x;

    __shared__ int scum[S];
    __shared__ int wsum[TB / 64];
    __shared__ int sidx[ROWS];

    // ---- inclusive scan of dur[b, :] into scum ----
    int v = dur[b * S + tid];
    #pragma unroll
    for (int off = 1; off < 64; off <<= 1) {
        int n = __shfl_up(v, off, 64);
        if ((tid & 63) >= off) v += n;
    }
    if ((tid & 63) == 63) wsum[tid >> 6] = v;
    __syncthreads();
    int add = 0;
    const int w = tid >> 6;
    #pragma unroll
    for (int i = 0; i < TB / 64; ++i)
        if (i < w) add += wsum[i];
    v += add;
    scum[tid] = v;
    __syncthreads();

    const int mel = scum[S - 1];
    if (rowblk == 0 && tid == S - 1) mel_out[b] = (float)v;  // v == scum[S-1]

    // ---- one binary search per output row (searchsorted right, clipped) ----
    if (tid < ROWS) {
        const int t = rowblk * ROWS + tid;
        int lo = 0, hi = S;
        while (lo < hi) {
            const int mid = (lo + hi) >> 1;
            if (scum[mid] <= t) lo = mid + 1; else hi = mid;
        }
        sidx[tid] = (lo < S) ? lo : (S - 1);
    }
    __syncthreads();

    // ---- gather rows from x (now XCD-L2-resident), coalesced stores ----
    const f32x4* xb = x + (size_t)b * S * D4;
    f32x4* ob = out + ((size_t)b * ML + (size_t)rowblk * ROWS) * D4;
    const f32x4 z = (f32x4){0.f, 0.f, 0.f, 0.f};

    #pragma unroll
    for (int j = tid; j < ROWS * D4; j += TB) {
        const int tl = j / D4;
        const int d4 = j - tl * D4;
        const int t  = rowblk * ROWS + tl;
        f32x4 vv = (t < mel) ? xb[(size_t)sidx[tl] * D4 + d4] : z;
        ob[j] = vv;
    }
}

extern "C" void kernel_launch(void* const* d_in, const int* in_sizes, int n_in,
                              void* d_out, int out_size, void* d_ws, size_t ws_size,
                              hipStream_t stream) {
    const float* x   = (const float*)d_in[0];
    const int*   dur = (const int*)d_in[1];
    float* out = (float*)d_out;
    float* mel_out = out + (size_t)B * ML * D;  // output-1 tail

    lr_fused_kernel<<<NWG, TB, 0, stream>>>(
        (const f32x4*)x, dur, (f32x4*)out, mel_out);
}